// Round 7
// baseline (231.551 us; speedup 1.0000x reference)
//
#include <hip/hip_runtime.h>
#include <hip/hip_fp16.h>
#include <math.h>

// ---------------------------------------------------------------------------
// GCN encoder. Aggregation = gather over a single-pass device-built ELL table.
// v2: XCD-sliced scatter (slice = blockIdx&7 -> per-XCD L2-resident ell slice).
// v3: 8-byte gather loads; dinv recomputed from cnt; 5 launches.
// v4/v5: wider loads / fewer VMEM -> flat. Gather is LATENCY-bound, not issue-
//        bound (6.4MB table vs 4MiB per-XCD L2 -> ~60% hit, queue-saturated).
// v6: source-half split for PHASE-PURE L2-resident gathers:
//     ELL split by src half (packed atomic: lo16=A-count, hi16=B-count).
//     Each conv = k_conv_part (gather half-A, 3.2MB hot, write f32 partials)
//     + k_conv*b (gather half-B, 3.2MB hot, + self + partials + epilogue).
// v6b: partials aliased onto out1 (d_out) -> workspace 32MB -> 19MB (v6's
//     container failure may have been ws overflow; 19MB < proven-fine 22.6MB).
//     Aliasing safe: conv2b reads part[node*16+2l] then writes out1 same addr,
//     same thread, program order; (node,l) ownership identical in both kernels.
// Rows are pre-scaled fp16: hs[r] = dinv[r]*(x@W1)[r], h2s[r] = dinv[r]*h2[r];
// self loop handled by seeding the accumulator with the node's own row.
// Gather entries beyond exact degree are clamped to a zero row.
// ---------------------------------------------------------------------------

#define ELLH 32   // per-half ELL width (deg/half ~ Poisson(8); P(>32) ~ 0)

typedef _Float16 half8 __attribute__((ext_vector_type(8)));
typedef float f32x4 __attribute__((ext_vector_type(4)));

// Pack W1 into f16 B-frag layout (4 col-tiles x 4 k-steps) and [W2|W3] into
// 5 tiles x 2 k-steps; blocks >= 52 zero the cnt array.
__global__ void k_setup(const float* __restrict__ W1, const float* __restrict__ W2,
                        const float* __restrict__ W3, _Float16* __restrict__ W1g,
                        _Float16* __restrict__ Bg, int* __restrict__ cnt, int n) {
    if (blockIdx.x >= 52) {
        int i = (blockIdx.x - 52) * 256 + threadIdx.x;
        if (i < n) cnt[i] = 0;
        return;
    }
    int idx = blockIdx.x * 256 + threadIdx.x;
    if (idx < 8192) {
        int j = idx & 7, L = (idx >> 3) & 63, s = (idx >> 9) & 3, t = idx >> 11;
        int k = s * 32 + (L >> 4) * 8 + j;
        int c = t * 16 + (L & 15);
        W1g[idx] = (_Float16)W1[k * 64 + c];
    } else if (idx < 8192 + 5120) {
        int i2 = idx - 8192;
        int j = i2 & 7, L = (i2 >> 3) & 63, s = (i2 >> 9) & 1, u = i2 >> 10;
        int k = s * 32 + (L >> 4) * 8 + j;
        int c = (L & 15);
        float v;
        if (u < 4) v = W2[k * 64 + u * 16 + c];
        else v = (c < 6) ? W3[k * 6 + c] : 0.f;
        Bg[i2] = (_Float16)v;
    }
}

// XCD-sliced single-pass dual-ELL build. Packed rank atomic:
// A-edge (src<halfN): cnt += 1 (rank = old&0xffff); B-edge: cnt += 1<<16.
__global__ __launch_bounds__(256) void k_scatter(
    const int* __restrict__ row, const int* __restrict__ col,
    int* __restrict__ cnt, int* __restrict__ ellA, int* __restrict__ ellB,
    int E, int slice_sz, int halfN) {
    int slice = blockIdx.x & 7;
    int lo = slice * slice_sz;
    int hi = lo + slice_sz;
    int stride = (gridDim.x >> 3) * 256;
    int v0 = (blockIdx.x >> 3) * 256 + threadIdx.x;
    int nv = E >> 2;
    const int4* c4p = (const int4*)col;
    const int4* r4p = (const int4*)row;
    auto sc1 = [&](int c, int r) {
        if (c >= lo && c < hi) {
            int hB = (r >= halfN) ? 1 : 0;
            int old = atomicAdd(&cnt[c], hB ? 0x10000 : 1);
            int rk = hB ? (old >> 16) : (old & 0xffff);
            int* tbl = hB ? ellB : ellA;
            if (rk < ELLH) tbl[c * ELLH + rk] = r << 7;
        }
    };
    for (int v = v0; v < nv; v += stride) {
        int4 c4 = c4p[v];
        int4 r4 = r4p[v];
        sc1(c4.x, r4.x);
        sc1(c4.y, r4.y);
        sc1(c4.z, r4.z);
        sc1(c4.w, r4.w);
    }
    if ((blockIdx.x >> 3) == 0) {        // tail edges (E % 4)
        for (int e = (nv << 2) + threadIdx.x; e < E; e += 256)
            sc1(col[e], row[e]);
    }
}

// hs = (x @ W1) * dinv, via f16 MFMA. Block = 4 waves x 16 nodes = 64 nodes.
__global__ __launch_bounds__(256, 4) void k_gemm1(
    const float* __restrict__ x, const _Float16* __restrict__ W1g,
    const int* __restrict__ cnt, uint* __restrict__ hs,
    uint* __restrict__ h2s, int n) {
    int tid = threadIdx.x;
    if (blockIdx.x == 0) {               // zero rows for clamped gathers
        if (tid < 32) hs[(size_t)n * 32 + tid] = 0u;
        else if (tid < 64) h2s[(size_t)n * 32 + (tid - 32)] = 0u;
    }
    int lane = tid & 63, wid = tid >> 6;
    int m16 = lane & 15, quad = lane >> 4;
    int node0 = blockIdx.x * 64 + wid * 16;
    int arow = node0 + m16;
    if (arow >= n) arow = n - 1;
    const float* xr = x + (size_t)arow * 128;
    half8 A[4];
#pragma unroll
    for (int s = 0; s < 4; s++) {
        const float4* p = (const float4*)(xr + s * 32 + quad * 8);
        float4 f0 = p[0], f1 = p[1];
        half8 a;
        a[0] = (_Float16)f0.x; a[1] = (_Float16)f0.y;
        a[2] = (_Float16)f0.z; a[3] = (_Float16)f0.w;
        a[4] = (_Float16)f1.x; a[5] = (_Float16)f1.y;
        a[6] = (_Float16)f1.z; a[7] = (_Float16)f1.w;
        A[s] = a;
    }
    float dsc[4];
#pragma unroll
    for (int r = 0; r < 4; r++) {
        int nd = node0 + quad * 4 + r;
        int cv = cnt[nd < n ? nd : n - 1];
        dsc[r] = rsqrtf((float)((cv & 0xffff) + (cv >> 16) + 1));
    }
    const half8* Wv = (const half8*)W1g;
#pragma unroll
    for (int t = 0; t < 4; t++) {
        f32x4 acc = {0.f, 0.f, 0.f, 0.f};
#pragma unroll
        for (int s = 0; s < 4; s++)
            acc = __builtin_amdgcn_mfma_f32_16x16x32_f16(A[s], Wv[(t * 4 + s) * 64 + lane], acc, 0, 0, 0);
#pragma unroll
        for (int r = 0; r < 4; r++) {
            int nd = node0 + quad * 4 + r;
            float v = acc[r] * dsc[r];
            float vo = __shfl_xor(v, 1, 64);
            if (!(m16 & 1) && nd < n) {
                __half2 pk = __floats2half2_rn(v, vo);
                hs[(size_t)nd * 32 + t * 8 + (m16 >> 1)] = *(uint*)&pk;
            }
        }
    }
}

// ---------------------------------------------------------------------------
// Gather core (v5 structure): lane = g*8 + l; l = 16B slice of the 128B row,
// g = edge group in [0,8). Per 8-edge step per node: 1 idx load + 1 uint4 row
// load per lane, depth-1 prefetch. accv[p][c] accumulates comps 8*l + c.
// ---------------------------------------------------------------------------
#define LDIX(TBL, Pq, p, jb) \
    ({ int _o = TBL[st[p] + (jb) + g]; ((jb) + g < Pq[p]) ? _o : zoff; })

#define CVT_ACC(p, U)                                                         \
    {                                                                         \
        float2 f;                                                             \
        f = __half22float2(*(__half2*)&U.x); accv[p][0] += f.x; accv[p][1] += f.y; \
        f = __half22float2(*(__half2*)&U.y); accv[p][2] += f.x; accv[p][3] += f.y; \
        f = __half22float2(*(__half2*)&U.z); accv[p][4] += f.x; accv[p][5] += f.y; \
        f = __half22float2(*(__half2*)&U.w); accv[p][6] += f.x; accv[p][7] += f.y; \
    }

#define GATHER_CORE(SRC, TBL, Pq, Pmaxv)                                      \
    {                                                                         \
        int oB[4], oC[4];                                                     \
        uint4 uA[4], uB[4];                                                   \
        _Pragma("unroll") for (int p = 0; p < 4; p++) {                       \
            int oA = LDIX(TBL, Pq, p, 0);                                     \
            oB[p] = LDIX(TBL, Pq, p, 8);                                      \
            uA[p] = *(const uint4*)(SRC + oA + m16b);                         \
        }                                                                     \
        for (int jb = 0; jb < Pmaxv; jb += 8) {                               \
            _Pragma("unroll") for (int p = 0; p < 4; p++) oC[p] = LDIX(TBL, Pq, p, jb + 16); \
            _Pragma("unroll") for (int p = 0; p < 4; p++)                     \
                uB[p] = *(const uint4*)(SRC + oB[p] + m16b);                  \
            _Pragma("unroll") for (int p = 0; p < 4; p++) CVT_ACC(p, uA[p])   \
            _Pragma("unroll") for (int p = 0; p < 4; p++) { uA[p] = uB[p]; oB[p] = oC[p]; } \
        }                                                                     \
    }

#define GATHER_REDUCE                                                         \
    _Pragma("unroll") for (int p = 0; p < 4; p++)                             \
        _Pragma("unroll") for (int c = 0; c < 8; c++) {                       \
            float v = accv[p][c];                                             \
            v += __shfl_xor(v, 8, 64);                                        \
            v += __shfl_xor(v, 16, 64);                                       \
            v += __shfl_xor(v, 32, 64);                                       \
            accv[p][c] = v;                                                   \
        }

// Phase-pure half-A gather: hot set = 3.2MB src half, L2-resident per XCD.
// Writes raw f32 partial sums (no self, no scale).
__global__ __launch_bounds__(256, 4) void k_conv_part(
    const uint* __restrict__ src, const int* __restrict__ ellA,
    const int* __restrict__ cnt, float* __restrict__ part, int zoff, int n) {
    int tid = threadIdx.x;
    int lane = tid & 63, wid = tid >> 6;
    int l = lane & 7, g = lane >> 3;
    int m16b = l * 16;
    int base = blockIdx.x * 16;
    int st[4], P[4];
    int Pmax = 0;
#pragma unroll
    for (int p = 0; p < 4; p++) {
        int node = base + wid * 4 + p;
        if (node >= n) node = n - 1;
        st[p] = node * ELLH;
        P[p] = cnt[node] & 0xffff;
        Pmax = Pmax > P[p] ? Pmax : P[p];
    }
    Pmax = (Pmax + 7) & ~7;
    const char* hsb = (const char*)src;
    float accv[4][8];
#pragma unroll
    for (int p = 0; p < 4; p++)
#pragma unroll
        for (int c = 0; c < 8; c++) accv[p][c] = 0.f;
    GATHER_CORE(hsb, ellA, P, Pmax)
    GATHER_REDUCE
#pragma unroll
    for (int p = 0; p < 4; p++) {
        int node = base + wid * 4 + p;
        if (g == 0 && node < n) {
            float4 q0 = {accv[p][0], accv[p][1], accv[p][2], accv[p][3]};
            float4 q1 = {accv[p][4], accv[p][5], accv[p][6], accv[p][7]};
            ((float4*)part)[(size_t)node * 16 + 2 * l] = q0;
            ((float4*)part)[(size_t)node * 16 + 2 * l + 1] = q1;
        }
    }
}

// conv1 phase B: gather half-B of hs + self + partials, LN+ReLU, then
// h2s & out2 via per-wave MFMA (same-wave LDS handoff, no barriers).
__global__ __launch_bounds__(256, 4) void k_conv1b(
    const uint* __restrict__ hs, const int* __restrict__ ellB,
    const int* __restrict__ cnt, const float* __restrict__ part,
    const float* __restrict__ b1, const float* __restrict__ lnw_g,
    const float* __restrict__ lnb_g, const _Float16* __restrict__ Bg,
    const float* __restrict__ b3, uint* __restrict__ h2s,
    float* __restrict__ out2, int zoff, int n) {
    __shared__ _Float16 Y[4][16 * 72];   // per-wave A tile, stride 72
    int tid = threadIdx.x;
    int lane = tid & 63, wid = tid >> 6;
    int l = lane & 7, g = lane >> 3;
    int m16b = l * 16;
    {   // zero my wave's tile (rows 4..15 stay zero for the MFMA)
        float4 z = {0.f, 0.f, 0.f, 0.f};
        float4* yb = (float4*)Y[wid];
        for (int i = lane; i < 144; i += 64) yb[i] = z;
    }
    int base = blockIdx.x * 16;
    int st[4], P[4], nid[4], dg[4];
    int Pmax = 0;
#pragma unroll
    for (int p = 0; p < 4; p++) {
        int node = base + wid * 4 + p;
        if (node >= n) node = n - 1;
        nid[p] = node;
        st[p] = node * ELLH;
        int cv = cnt[node];
        P[p] = cv >> 16;
        dg[p] = (cv & 0xffff) + (cv >> 16);
        Pmax = Pmax > P[p] ? Pmax : P[p];
    }
    Pmax = (Pmax + 7) & ~7;
    const char* hsb = (const char*)hs;
    float accv[4][8];
#pragma unroll
    for (int p = 0; p < 4; p++) {        // seed with own (pre-scaled) row
        int sa = (g == 0) ? (nid[p] << 7) : zoff;
        uint4 us = *(const uint4*)(hsb + sa + m16b);
        float2 f;
        f = __half22float2(*(__half2*)&us.x); accv[p][0] = f.x; accv[p][1] = f.y;
        f = __half22float2(*(__half2*)&us.y); accv[p][2] = f.x; accv[p][3] = f.y;
        f = __half22float2(*(__half2*)&us.z); accv[p][4] = f.x; accv[p][5] = f.y;
        f = __half22float2(*(__half2*)&us.w); accv[p][6] = f.x; accv[p][7] = f.y;
    }
    GATHER_CORE(hsb, ellB, P, Pmax)
    GATHER_REDUCE
    {   // add half-A partials (dup across g; lanes share lines -> coalesced)
        const float4* pf = (const float4*)part;
#pragma unroll
        for (int p = 0; p < 4; p++) {
            float4 q0 = pf[(size_t)nid[p] * 16 + 2 * l];
            float4 q1 = pf[(size_t)nid[p] * 16 + 2 * l + 1];
            accv[p][0] += q0.x; accv[p][1] += q0.y;
            accv[p][2] += q0.z; accv[p][3] += q0.w;
            accv[p][4] += q1.x; accv[p][5] += q1.y;
            accv[p][6] += q1.z; accv[p][7] += q1.w;
        }
    }

    // LN + ReLU: lane owns comps 8l..8l+7 (duplicated across g); row reduce
    // is xor 1,2,4 (l bits). Write y rows (f16, 16B/lane from g==0) to Y tile.
    float4 bvlo = ((const float4*)b1)[2 * l], bvhi = ((const float4*)b1)[2 * l + 1];
    float4 lwlo = ((const float4*)lnw_g)[2 * l], lwhi = ((const float4*)lnw_g)[2 * l + 1];
    float4 lblo = ((const float4*)lnb_g)[2 * l], lbhi = ((const float4*)lnb_g)[2 * l + 1];
    float dcs[4];
#pragma unroll
    for (int p = 0; p < 4; p++) {
        float dc = rsqrtf((float)(dg[p] + 1));
        dcs[p] = dc;
        float v[8];
        v[0] = fmaf(dc, accv[p][0], bvlo.x); v[1] = fmaf(dc, accv[p][1], bvlo.y);
        v[2] = fmaf(dc, accv[p][2], bvlo.z); v[3] = fmaf(dc, accv[p][3], bvlo.w);
        v[4] = fmaf(dc, accv[p][4], bvhi.x); v[5] = fmaf(dc, accv[p][5], bvhi.y);
        v[6] = fmaf(dc, accv[p][6], bvhi.z); v[7] = fmaf(dc, accv[p][7], bvhi.w);
        float s = ((v[0] + v[1]) + (v[2] + v[3])) + ((v[4] + v[5]) + (v[6] + v[7]));
        s += __shfl_xor(s, 1, 64); s += __shfl_xor(s, 2, 64); s += __shfl_xor(s, 4, 64);
        float mu = s * (1.f / 64.f);
        float d[8], q = 0.f;
#pragma unroll
        for (int c = 0; c < 8; c++) { d[c] = v[c] - mu; q += d[c] * d[c]; }
        q += __shfl_xor(q, 1, 64); q += __shfl_xor(q, 2, 64); q += __shfl_xor(q, 4, 64);
        float rstd = rsqrtf(q * (1.f / 64.f) + 1e-5f);
        float y[8];
        y[0] = fmaxf(fmaf(d[0] * rstd, lwlo.x, lblo.x), 0.f);
        y[1] = fmaxf(fmaf(d[1] * rstd, lwlo.y, lblo.y), 0.f);
        y[2] = fmaxf(fmaf(d[2] * rstd, lwlo.z, lblo.z), 0.f);
        y[3] = fmaxf(fmaf(d[3] * rstd, lwlo.w, lblo.w), 0.f);
        y[4] = fmaxf(fmaf(d[4] * rstd, lwhi.x, lbhi.x), 0.f);
        y[5] = fmaxf(fmaf(d[5] * rstd, lwhi.y, lbhi.y), 0.f);
        y[6] = fmaxf(fmaf(d[6] * rstd, lwhi.z, lbhi.z), 0.f);
        y[7] = fmaxf(fmaf(d[7] * rstd, lwhi.w, lbhi.w), 0.f);
        if (g == 0) {                    // 8 lanes x 16B = full 128B row
            __half2 pk0 = __floats2half2_rn(y[0], y[1]);
            __half2 pk1 = __floats2half2_rn(y[2], y[3]);
            __half2 pk2 = __floats2half2_rn(y[4], y[5]);
            __half2 pk3 = __floats2half2_rn(y[6], y[7]);
            uint4 pk;
            pk.x = *(uint*)&pk0; pk.y = *(uint*)&pk1;
            pk.z = *(uint*)&pk2; pk.w = *(uint*)&pk3;
            *(uint4*)&Y[wid][p * 72 + 8 * l] = pk;   // byte p*144+16l, 16B-aligned
        }
    }
    // same-wave LDS producer/consumer: lgkmcnt wait only, no barrier
    int m16 = lane & 15, quad = lane >> 4;
    half8 a0 = *(const half8*)&Y[wid][m16 * 72 + quad * 8];
    half8 a1 = *(const half8*)&Y[wid][m16 * 72 + 32 + quad * 8];
    const half8* Bv = (const half8*)Bg;
    _Float16* h2h = (_Float16*)h2s;
#pragma unroll
    for (int t = 0; t < 4; t++) {        // h2 = y @ W2 (4 col tiles)
        f32x4 acc2 = {0.f, 0.f, 0.f, 0.f};
        acc2 = __builtin_amdgcn_mfma_f32_16x16x32_f16(a0, Bv[(t * 2 + 0) * 64 + lane], acc2, 0, 0, 0);
        acc2 = __builtin_amdgcn_mfma_f32_16x16x32_f16(a1, Bv[(t * 2 + 1) * 64 + lane], acc2, 0, 0, 0);
#pragma unroll
        for (int r = 0; r < 4; r++) {    // C row quad*4+r: real rows live in quad 0
            int nodep = base + wid * 4 + r;
            if (quad == 0 && nodep < n)
                h2h[(size_t)nodep * 64 + t * 16 + m16] = (_Float16)(acc2[r] * dcs[r]);
        }
    }
    {                                    // out2 = sigmoid(y @ W3 + b3)
        f32x4 acc2 = {0.f, 0.f, 0.f, 0.f};
        acc2 = __builtin_amdgcn_mfma_f32_16x16x32_f16(a0, Bv[8 * 64 + lane], acc2, 0, 0, 0);
        acc2 = __builtin_amdgcn_mfma_f32_16x16x32_f16(a1, Bv[9 * 64 + lane], acc2, 0, 0, 0);
        float bb = b3[m16 < 6 ? m16 : 0];
#pragma unroll
        for (int r = 0; r < 4; r++) {
            int nodep = base + wid * 4 + r;
            if (quad == 0 && m16 < 6 && nodep < n)
                out2[(size_t)nodep * 6 + m16] = 1.f / (1.f + __expf(-(acc2[r] + bb)));
        }
    }
}

// conv2 phase B: out1 = dc * (self + sumB + partA) + b2.
// part aliases out1: per-(node,l) read-then-write by the same thread -> safe.
__global__ __launch_bounds__(256, 4) void k_conv2b(
    const uint* __restrict__ h2s, const int* __restrict__ ellB,
    const int* __restrict__ cnt, const float* __restrict__ part,
    const float* __restrict__ b2, float* __restrict__ out1, int zoff, int n) {
    int tid = threadIdx.x;
    int lane = tid & 63, wid = tid >> 6;
    int l = lane & 7, g = lane >> 3;
    int m16b = l * 16;
    int base = blockIdx.x * 16;
    int st[4], P[4], nid[4], dg[4];
    int Pmax = 0;
#pragma unroll
    for (int p = 0; p < 4; p++) {
        int node = base + wid * 4 + p;
        if (node >= n) node = n - 1;
        nid[p] = node;
        st[p] = node * ELLH;
        int cv = cnt[node];
        P[p] = cv >> 16;
        dg[p] = (cv & 0xffff) + (cv >> 16);
        Pmax = Pmax > P[p] ? Pmax : P[p];
    }
    Pmax = (Pmax + 7) & ~7;
    const char* hsb = (const char*)h2s;
    float accv[4][8];
#pragma unroll
    for (int p = 0; p < 4; p++) {        // seed with own row
        int sa = (g == 0) ? (nid[p] << 7) : zoff;
        uint4 us = *(const uint4*)(hsb + sa + m16b);
        float2 f;
        f = __half22float2(*(__half2*)&us.x); accv[p][0] = f.x; accv[p][1] = f.y;
        f = __half22float2(*(__half2*)&us.y); accv[p][2] = f.x; accv[p][3] = f.y;
        f = __half22float2(*(__half2*)&us.z); accv[p][4] = f.x; accv[p][5] = f.y;
        f = __half22float2(*(__half2*)&us.w); accv[p][6] = f.x; accv[p][7] = f.y;
    }
    GATHER_CORE(hsb, ellB, P, Pmax)
    GATHER_REDUCE

    const float4* pf = (const float4*)part;
    float4 b2lo = ((const float4*)b2)[2 * l], b2hi = ((const float4*)b2)[2 * l + 1];
#pragma unroll
    for (int p = 0; p < 4; p++) {
        int node = base + wid * 4 + p;
        if (g == 0 && node < n) {
            float dc = rsqrtf((float)(dg[p] + 1));
            float4 q0 = pf[(size_t)node * 16 + 2 * l];
            float4 q1 = pf[(size_t)node * 16 + 2 * l + 1];
            float4 r0, r1;
            r0.x = fmaf(dc, accv[p][0] + q0.x, b2lo.x);
            r0.y = fmaf(dc, accv[p][1] + q0.y, b2lo.y);
            r0.z = fmaf(dc, accv[p][2] + q0.z, b2lo.z);
            r0.w = fmaf(dc, accv[p][3] + q0.w, b2lo.w);
            r1.x = fmaf(dc, accv[p][4] + q1.x, b2hi.x);
            r1.y = fmaf(dc, accv[p][5] + q1.y, b2hi.y);
            r1.z = fmaf(dc, accv[p][6] + q1.z, b2hi.z);
            r1.w = fmaf(dc, accv[p][7] + q1.w, b2hi.w);
            ((float4*)out1)[(size_t)node * 16 + 2 * l] = r0;
            ((float4*)out1)[(size_t)node * 16 + 2 * l + 1] = r1;
        }
    }
}

extern "C" void kernel_launch(void* const* d_in, const int* in_sizes, int n_in,
                              void* d_out, int out_size, void* d_ws, size_t ws_size,
                              hipStream_t stream) {
    const float* x   = (const float*)d_in[0];
    const int*   ei  = (const int*)d_in[1];
    const float* W1  = (const float*)d_in[2];
    const float* b1  = (const float*)d_in[3];
    const float* lnw = (const float*)d_in[4];
    const float* lnb = (const float*)d_in[5];
    const float* W2  = (const float*)d_in[6];
    const float* b2  = (const float*)d_in[7];
    const float* W3  = (const float*)d_in[8];
    const float* b3  = (const float*)d_in[9];

    int n = in_sizes[0] / 128;
    int E = in_sizes[1] / 2;
    const int* row = ei;        // sources
    const int* col = ei + E;    // targets

    char* ws = (char*)d_ws;
    size_t off = 0;
    auto carve = [&](size_t bytes) -> char* {
        char* p = ws + off;
        off = (off + bytes + 255) & ~(size_t)255;
        return p;
    };
    int*   cnt  = (int*)carve(4 * (size_t)n);
    int*   ellA = (int*)carve(4 * ((size_t)n * ELLH + 64));   // +margin for prefetch
    int*   ellB = (int*)carve(4 * ((size_t)n * ELLH + 64));
    uint*  hs   = (uint*)carve(128 * ((size_t)n + 1));        // +1 zero row
    uint*  h2s  = (uint*)carve(128 * ((size_t)n + 1));
    _Float16* W1g = (_Float16*)carve(2 * 8192);
    _Float16* Bg  = (_Float16*)carve(2 * 5120);

    float* out1 = (float*)d_out;
    float* out2 = out1 + (size_t)n * 64;
    float* part = out1;                  // partials alias out1 (see k_conv2b)
    int zero_off = n << 7;
    int slice_sz = (n + 7) / 8;          // contiguous node slice per XCD
    int halfN = n >> 1;

    k_setup<<<52 + (n + 255) / 256, 256, 0, stream>>>(W1, W2, W3, W1g, Bg, cnt, n);
    k_scatter<<<8 * 256, 256, 0, stream>>>(row, col, cnt, ellA, ellB, E,
                                           slice_sz, halfN);
    k_gemm1<<<(n + 63) / 64, 256, 0, stream>>>(x, W1g, cnt, hs, h2s, n);
    int cg = (n + 15) / 16;
    k_conv_part<<<cg, 256, 0, stream>>>(hs, ellA, cnt, part, zero_off, n);
    k_conv1b<<<cg, 256, 0, stream>>>(hs, ellB, cnt, part, b1, lnw, lnb,
                                     Bg, b3, h2s, out2, zero_off, n);
    k_conv_part<<<cg, 256, 0, stream>>>(h2s, ellA, cnt, part, zero_off, n);
    k_conv2b<<<cg, 256, 0, stream>>>(h2s, ellB, cnt, part, b2,
                                     out1, zero_off, n);
}

// Round 8
// 182.152 us; speedup vs baseline: 1.2712x; 1.2712x over previous
//
#include <hip/hip_runtime.h>
#include <hip/hip_fp16.h>
#include <math.h>

// ---------------------------------------------------------------------------
// GCN encoder. Aggregation = gather over a single-pass device-built ELL table:
//   k_scatter: r = atomicAdd(&cnt[c],1); ell[c*48+r] = src_row_byte_offset
// v2: XCD-sliced scatter (slice = blockIdx&7 -> per-XCD L2-resident ell slice).
// v3: 8-byte gather loads; dinv recomputed from cnt; 5 launches. [champion 187.6]
// v4/v5: wider loads / deeper prefetch -> flat (gather latency-bound).
// v6: source-half phase split -> REGRESSED (doubled pass overhead > L2 gain).
// v7: OCCUPANCY: conv kernels 2 nodes/wave (was 4) -> ~60 VGPR peak ->
//     __launch_bounds__(256,8) -> 8 waves/SIMD (was 4) -> 2x in-flight gather
//     loads per CU. Grid doubles; MFMA epilogue cost 2x (~few us, acceptable).
// Rows are pre-scaled fp16: hs[r] = dinv[r]*(x@W1)[r], h2s[r] = dinv[r]*h2[r];
// self loop is handled by initializing the accumulator from the node's own row.
// Gather entries beyond exact degree are clamped (cndmask) to a zero row.
// ---------------------------------------------------------------------------

#define ELLW 48

typedef _Float16 half8 __attribute__((ext_vector_type(8)));
typedef float f32x4 __attribute__((ext_vector_type(4)));

// Pack W1 into f16 B-frag layout (4 col-tiles x 4 k-steps) and [W2|W3] into
// 5 tiles x 2 k-steps; blocks >= 52 zero the cnt array.
__global__ void k_setup(const float* __restrict__ W1, const float* __restrict__ W2,
                        const float* __restrict__ W3, _Float16* __restrict__ W1g,
                        _Float16* __restrict__ Bg, int* __restrict__ cnt, int n) {
    if (blockIdx.x >= 52) {
        int i = (blockIdx.x - 52) * 256 + threadIdx.x;
        if (i < n) cnt[i] = 0;
        return;
    }
    int idx = blockIdx.x * 256 + threadIdx.x;
    if (idx < 8192) {
        int j = idx & 7, L = (idx >> 3) & 63, s = (idx >> 9) & 3, t = idx >> 11;
        int k = s * 32 + (L >> 4) * 8 + j;
        int c = t * 16 + (L & 15);
        W1g[idx] = (_Float16)W1[k * 64 + c];
    } else if (idx < 8192 + 5120) {
        int i2 = idx - 8192;
        int j = i2 & 7, L = (i2 >> 3) & 63, s = (i2 >> 9) & 1, u = i2 >> 10;
        int k = s * 32 + (L >> 4) * 8 + j;
        int c = (L & 15);
        float v;
        if (u < 4) v = W2[k * 64 + u * 16 + c];
        else v = (c < 6) ? W3[k * 6 + c] : 0.f;
        Bg[i2] = (_Float16)v;
    }
}

// XCD-sliced single-pass ELL build: rank comes from the atomic itself.
// slice = blockIdx&7 -> round-robin XCD mapping; each slice's cnt+ell working
// set (~25KB + ~1.2MB) stays resident in that XCD's L2 so writebacks merge.
__global__ __launch_bounds__(256) void k_scatter(
    const int* __restrict__ row, const int* __restrict__ col,
    int* __restrict__ cnt, int* __restrict__ ell, int E, int slice_sz) {
    int slice = blockIdx.x & 7;
    int lo = slice * slice_sz;
    int hi = lo + slice_sz;
    int nchunk = gridDim.x >> 3;
    int stride = nchunk * 256;
    int v0 = (blockIdx.x >> 3) * 256 + threadIdx.x;
    int nv = E >> 2;
    const int4* c4p = (const int4*)col;
    const int4* r4p = (const int4*)row;
    for (int v = v0; v < nv; v += stride) {
        int4 c4 = c4p[v];
        int4 r4 = r4p[v];
        if (c4.x >= lo && c4.x < hi) {
            int rk = atomicAdd(&cnt[c4.x], 1);
            if (rk < ELLW) ell[c4.x * ELLW + rk] = r4.x << 7;
        }
        if (c4.y >= lo && c4.y < hi) {
            int rk = atomicAdd(&cnt[c4.y], 1);
            if (rk < ELLW) ell[c4.y * ELLW + rk] = r4.y << 7;
        }
        if (c4.z >= lo && c4.z < hi) {
            int rk = atomicAdd(&cnt[c4.z], 1);
            if (rk < ELLW) ell[c4.z * ELLW + rk] = r4.z << 7;
        }
        if (c4.w >= lo && c4.w < hi) {
            int rk = atomicAdd(&cnt[c4.w], 1);
            if (rk < ELLW) ell[c4.w * ELLW + rk] = r4.w << 7;
        }
    }
    if ((blockIdx.x >> 3) == 0) {        // tail edges (E % 4)
        for (int e = (nv << 2) + threadIdx.x; e < E; e += 256) {
            int c = col[e];
            if (c >= lo && c < hi) {
                int rk = atomicAdd(&cnt[c], 1);
                if (rk < ELLW) ell[c * ELLW + rk] = row[e] << 7;
            }
        }
    }
}

// hs = (x @ W1) * dinv, via f16 MFMA. Block = 4 waves x 16 nodes = 64 nodes.
__global__ __launch_bounds__(256, 4) void k_gemm1(
    const float* __restrict__ x, const _Float16* __restrict__ W1g,
    const int* __restrict__ cnt, uint* __restrict__ hs,
    uint* __restrict__ h2s, int n) {
    int tid = threadIdx.x;
    if (blockIdx.x == 0) {               // zero rows for clamped gathers
        if (tid < 32) hs[(size_t)n * 32 + tid] = 0u;
        else if (tid < 64) h2s[(size_t)n * 32 + (tid - 32)] = 0u;
    }
    int lane = tid & 63, wid = tid >> 6;
    int m16 = lane & 15, quad = lane >> 4;
    int node0 = blockIdx.x * 64 + wid * 16;
    int arow = node0 + m16;
    if (arow >= n) arow = n - 1;
    const float* xr = x + (size_t)arow * 128;
    half8 A[4];
#pragma unroll
    for (int s = 0; s < 4; s++) {
        const float4* p = (const float4*)(xr + s * 32 + quad * 8);
        float4 f0 = p[0], f1 = p[1];
        half8 a;
        a[0] = (_Float16)f0.x; a[1] = (_Float16)f0.y;
        a[2] = (_Float16)f0.z; a[3] = (_Float16)f0.w;
        a[4] = (_Float16)f1.x; a[5] = (_Float16)f1.y;
        a[6] = (_Float16)f1.z; a[7] = (_Float16)f1.w;
        A[s] = a;
    }
    float dsc[4];
#pragma unroll
    for (int r = 0; r < 4; r++) {
        int nd = node0 + quad * 4 + r;
        dsc[r] = rsqrtf((float)(cnt[nd < n ? nd : n - 1] + 1));
    }
    const half8* Wv = (const half8*)W1g;
#pragma unroll
    for (int t = 0; t < 4; t++) {
        f32x4 acc = {0.f, 0.f, 0.f, 0.f};
#pragma unroll
        for (int s = 0; s < 4; s++)
            acc = __builtin_amdgcn_mfma_f32_16x16x32_f16(A[s], Wv[(t * 4 + s) * 64 + lane], acc, 0, 0, 0);
#pragma unroll
        for (int r = 0; r < 4; r++) {
            int nd = node0 + quad * 4 + r;
            float v = acc[r] * dsc[r];
            float vo = __shfl_xor(v, 1, 64);
            if (!(m16 & 1) && nd < n) {
                __half2 pk = __floats2half2_rn(v, vo);
                hs[(size_t)nd * 32 + t * 8 + (m16 >> 1)] = *(uint*)&pk;
            }
        }
    }
}

// ---------------------------------------------------------------------------
// v7 gather: 2 nodes/wave. lane = g*16 + m16l; m16l = 8B slice of the 128B
// row (16 lanes x uint2), g = edge pair group in [0,4). Per 8-edge step per
// node: 1 idx int2 load + 2 uint2 row loads per lane, depth-1 prefetch.
// accv[p][c] accumulates comps 4*m16l + c. Cross-group reduce at the end.
// ---------------------------------------------------------------------------
#define GATHER_PROLOG2(SRC_T)                                                 \
    int st[2], P[2], nid[2];                                                  \
    int Pmax = 0;                                                             \
    _Pragma("unroll") for (int p = 0; p < 2; p++) {                           \
        int node = base + wid * 2 + p;                                        \
        if (node >= n) node = n - 1;                                          \
        nid[p] = node; st[p] = node * ELLW; P[p] = cnt[node];                 \
        Pmax = Pmax > P[p] ? Pmax : P[p];                                     \
    }                                                                         \
    Pmax = (Pmax + 7) & ~7;                                                   \
    auto ldidx2 = [&](int p, int jb) -> int2 {                                \
        int2 o = *(const int2*)(ell + st[p] + jb + 2 * g);                    \
        int b = jb + 2 * g;                                                   \
        o.x = (b + 0 < P[p]) ? o.x : zoff;                                    \
        o.y = (b + 1 < P[p]) ? o.y : zoff;                                    \
        return o;                                                             \
    };                                                                        \
    const char* hsb = (const char*)(SRC_T);                                   \
    float accv[2][4];                                                         \
    _Pragma("unroll") for (int p = 0; p < 2; p++) {                           \
        int sa = (g == 0) ? (nid[p] << 7) : zoff;                             \
        uint2 us = *(const uint2*)(hsb + sa + m8);                            \
        float2 f0 = __half22float2(*(__half2*)&us.x);                         \
        float2 f1 = __half22float2(*(__half2*)&us.y);                         \
        accv[p][0] = f0.x; accv[p][1] = f0.y;                                 \
        accv[p][2] = f1.x; accv[p][3] = f1.y;                                 \
    }

#define GATHER_BODY2(SRC)                                                     \
    {                                                                         \
        int2 o1[2], o2[2];                                                    \
        uint4 u0[2], u1[2];                                                   \
        {                                                                     \
            int2 o0[2];                                                       \
            _Pragma("unroll") for (int p = 0; p < 2; p++) o0[p] = ldidx2(p, 0); \
            _Pragma("unroll") for (int p = 0; p < 2; p++) o1[p] = ldidx2(p, 8); \
            _Pragma("unroll") for (int p = 0; p < 2; p++) {                   \
                uint2 t0 = *(const uint2*)(SRC + o0[p].x + m8);               \
                uint2 t1 = *(const uint2*)(SRC + o0[p].y + m8);               \
                u0[p].x = t0.x; u0[p].y = t0.y; u0[p].z = t1.x; u0[p].w = t1.y; \
            }                                                                 \
        }                                                                     \
        for (int jb = 0; jb < Pmax; jb += 8) {                                \
            _Pragma("unroll") for (int p = 0; p < 2; p++) o2[p] = ldidx2(p, jb + 16); \
            _Pragma("unroll") for (int p = 0; p < 2; p++) {                   \
                uint2 t0 = *(const uint2*)(SRC + o1[p].x + m8);               \
                uint2 t1 = *(const uint2*)(SRC + o1[p].y + m8);               \
                u1[p].x = t0.x; u1[p].y = t0.y; u1[p].z = t1.x; u1[p].w = t1.y; \
            }                                                                 \
            _Pragma("unroll") for (int p = 0; p < 2; p++) {                   \
                float2 f;                                                     \
                f = __half22float2(*(__half2*)&u0[p].x); accv[p][0] += f.x; accv[p][1] += f.y; \
                f = __half22float2(*(__half2*)&u0[p].y); accv[p][2] += f.x; accv[p][3] += f.y; \
                f = __half22float2(*(__half2*)&u0[p].z); accv[p][0] += f.x; accv[p][1] += f.y; \
                f = __half22float2(*(__half2*)&u0[p].w); accv[p][2] += f.x; accv[p][3] += f.y; \
            }                                                                 \
            _Pragma("unroll") for (int p = 0; p < 2; p++) { u0[p] = u1[p]; o1[p] = o2[p]; } \
        }                                                                     \
    }                                                                         \
    _Pragma("unroll") for (int p = 0; p < 2; p++)                             \
        _Pragma("unroll") for (int c = 0; c < 4; c++) {                       \
            float v = accv[p][c];                                             \
            v += __shfl_xor(v, 16, 64);                                       \
            v += __shfl_xor(v, 32, 64);                                       \
            accv[p][c] = v;                                                   \
        }

// conv1 + bias + LN + ReLU, then h2s & out2 via per-wave MFMA. No barriers.
// 2 nodes/wave, 8 nodes/block, 8 waves/SIMD target.
__global__ __launch_bounds__(256, 8) void k_conv1_fused(
    const uint* __restrict__ hs, const int* __restrict__ ell,
    const int* __restrict__ cnt, const float* __restrict__ b1,
    const float* __restrict__ lnw_g, const float* __restrict__ lnb_g,
    const _Float16* __restrict__ Bg, const float* __restrict__ b3,
    uint* __restrict__ h2s, float* __restrict__ out2, int zoff, int n) {
    __shared__ _Float16 Y[4][16 * 72];   // per-wave A tile, stride 72
    int tid = threadIdx.x;
    int lane = tid & 63, wid = tid >> 6;
    int m16l = lane & 15, g = lane >> 4;
    int m8 = m16l * 8;
    {   // zero my wave's tile (rows 2..15 stay zero for the MFMA)
        float4 z = {0.f, 0.f, 0.f, 0.f};
        float4* yb = (float4*)Y[wid];
        for (int i = lane; i < 144; i += 64) yb[i] = z;
    }
    int base = blockIdx.x * 8;
    GATHER_PROLOG2(hs)
    GATHER_BODY2(hsb)

    // LN + ReLU: lane m16l owns comps 4m..4m+3 (dup across g); row reduce is
    // xor 8,4,2,1. Write y rows (f16, 8B/lane from g==0) to the wave's Y tile.
    float4 b1v = ((const float4*)b1)[m16l];
    float4 lw = ((const float4*)lnw_g)[m16l];
    float4 lb = ((const float4*)lnb_g)[m16l];
    float dcs[2];
#pragma unroll
    for (int p = 0; p < 2; p++) {
        float dc = rsqrtf((float)(P[p] + 1));
        dcs[p] = dc;
        float v0 = fmaf(dc, accv[p][0], b1v.x);
        float v1 = fmaf(dc, accv[p][1], b1v.y);
        float v2 = fmaf(dc, accv[p][2], b1v.z);
        float v3 = fmaf(dc, accv[p][3], b1v.w);
        float s = (v0 + v1) + (v2 + v3);
#pragma unroll
        for (int off = 8; off > 0; off >>= 1) s += __shfl_xor(s, off, 64);
        float mu = s * (1.f / 64.f);
        float d0 = v0 - mu, d1 = v1 - mu, d2 = v2 - mu, d3 = v3 - mu;
        float q = d0 * d0 + d1 * d1 + d2 * d2 + d3 * d3;
#pragma unroll
        for (int off = 8; off > 0; off >>= 1) q += __shfl_xor(q, off, 64);
        float rstd = rsqrtf(q * (1.f / 64.f) + 1e-5f);
        float y0 = fmaxf(fmaf(d0 * rstd, lw.x, lb.x), 0.f);
        float y1 = fmaxf(fmaf(d1 * rstd, lw.y, lb.y), 0.f);
        float y2 = fmaxf(fmaf(d2 * rstd, lw.z, lb.z), 0.f);
        float y3 = fmaxf(fmaf(d3 * rstd, lw.w, lb.w), 0.f);
        if (g == 0) {
            __half2 pk0 = __floats2half2_rn(y0, y1);
            __half2 pk1 = __floats2half2_rn(y2, y3);
            uint2 pk;
            pk.x = *(uint*)&pk0; pk.y = *(uint*)&pk1;
            *(uint2*)&Y[wid][p * 72 + 4 * m16l] = pk;
        }
    }
    // same-wave LDS producer/consumer: lgkmcnt wait only, no barrier
    int m16 = lane & 15, quad = lane >> 4;
    half8 a0 = *(const half8*)&Y[wid][m16 * 72 + quad * 8];
    half8 a1 = *(const half8*)&Y[wid][m16 * 72 + 32 + quad * 8];
    const half8* Bv = (const half8*)Bg;
    _Float16* h2h = (_Float16*)h2s;
#pragma unroll
    for (int t = 0; t < 4; t++) {        // h2 = y @ W2 (4 col tiles)
        f32x4 acc2 = {0.f, 0.f, 0.f, 0.f};
        acc2 = __builtin_amdgcn_mfma_f32_16x16x32_f16(a0, Bv[(t * 2 + 0) * 64 + lane], acc2, 0, 0, 0);
        acc2 = __builtin_amdgcn_mfma_f32_16x16x32_f16(a1, Bv[(t * 2 + 1) * 64 + lane], acc2, 0, 0, 0);
#pragma unroll
        for (int r = 0; r < 2; r++) {    // real rows live in quad 0, r<2
            int nodep = base + wid * 2 + r;
            if (quad == 0 && nodep < n)
                h2h[(size_t)nodep * 64 + t * 16 + m16] = (_Float16)(acc2[r] * dcs[r]);
        }
    }
    {                                    // out2 = sigmoid(y @ W3 + b3)
        f32x4 acc2 = {0.f, 0.f, 0.f, 0.f};
        acc2 = __builtin_amdgcn_mfma_f32_16x16x32_f16(a0, Bv[8 * 64 + lane], acc2, 0, 0, 0);
        acc2 = __builtin_amdgcn_mfma_f32_16x16x32_f16(a1, Bv[9 * 64 + lane], acc2, 0, 0, 0);
        float bb = b3[m16 < 6 ? m16 : 0];
#pragma unroll
        for (int r = 0; r < 2; r++) {
            int nodep = base + wid * 2 + r;
            if (quad == 0 && m16 < 6 && nodep < n)
                out2[(size_t)nodep * 6 + m16] = 1.f / (1.f + __expf(-(acc2[r] + bb)));
        }
    }
}

// conv2: out1 = dc * (self + sum(h2s[slice])) + b2. 2 nodes/wave.
__global__ __launch_bounds__(256, 8) void k_conv2(
    const uint* __restrict__ h2s, const int* __restrict__ ell,
    const int* __restrict__ cnt, const float* __restrict__ b2,
    float* __restrict__ out1, int zoff, int n) {
    int tid = threadIdx.x;
    int lane = tid & 63, wid = tid >> 6;
    int m16l = lane & 15, g = lane >> 4;
    int m8 = m16l * 8;
    int base = blockIdx.x * 8;
    GATHER_PROLOG2(h2s)
    GATHER_BODY2(hsb)

    float4 b2v = ((const float4*)b2)[m16l];
#pragma unroll
    for (int p = 0; p < 2; p++) {
        int node = base + wid * 2 + p;
        if (g == 0 && node < n) {
            float dc = rsqrtf((float)(P[p] + 1));
            float4 r;
            r.x = fmaf(dc, accv[p][0], b2v.x);
            r.y = fmaf(dc, accv[p][1], b2v.y);
            r.z = fmaf(dc, accv[p][2], b2v.z);
            r.w = fmaf(dc, accv[p][3], b2v.w);
            ((float4*)out1)[(size_t)node * 16 + m16l] = r;
        }
    }
}

extern "C" void kernel_launch(void* const* d_in, const int* in_sizes, int n_in,
                              void* d_out, int out_size, void* d_ws, size_t ws_size,
                              hipStream_t stream) {
    const float* x   = (const float*)d_in[0];
    const int*   ei  = (const int*)d_in[1];
    const float* W1  = (const float*)d_in[2];
    const float* b1  = (const float*)d_in[3];
    const float* lnw = (const float*)d_in[4];
    const float* lnb = (const float*)d_in[5];
    const float* W2  = (const float*)d_in[6];
    const float* b2  = (const float*)d_in[7];
    const float* W3  = (const float*)d_in[8];
    const float* b3  = (const float*)d_in[9];

    int n = in_sizes[0] / 128;
    int E = in_sizes[1] / 2;
    const int* row = ei;        // sources
    const int* col = ei + E;    // targets

    char* ws = (char*)d_ws;
    size_t off = 0;
    auto carve = [&](size_t bytes) -> char* {
        char* p = ws + off;
        off = (off + bytes + 255) & ~(size_t)255;
        return p;
    };
    int*   cnt  = (int*)carve(4 * (size_t)n);
    int*   ell  = (int*)carve(4 * ((size_t)n * ELLW + 256));  // +margin for prefetch
    uint*  hs   = (uint*)carve(128 * ((size_t)n + 1));        // +1 zero row
    uint*  h2s  = (uint*)carve(128 * ((size_t)n + 1));
    _Float16* W1g = (_Float16*)carve(2 * 8192);
    _Float16* Bg  = (_Float16*)carve(2 * 5120);

    float* out1 = (float*)d_out;
    float* out2 = out1 + (size_t)n * 64;
    int zero_off = n << 7;
    int slice_sz = (n + 7) / 8;          // contiguous node slice per XCD

    k_setup<<<52 + (n + 255) / 256, 256, 0, stream>>>(W1, W2, W3, W1g, Bg, cnt, n);
    // 8 slices x 256 edge-chunks; blockIdx&7 = slice -> XCD round-robin
    k_scatter<<<8 * 256, 256, 0, stream>>>(row, col, cnt, ell, E, slice_sz);
    k_gemm1<<<(n + 63) / 64, 256, 0, stream>>>(x, W1g, cnt, hs, h2s, n);
    int cg = (n + 7) / 8;                // 8 nodes per block (2/wave)
    k_conv1_fused<<<cg, 256, 0, stream>>>(hs, ell, cnt,
                                          b1, lnw, lnb, Bg, b3,
                                          h2s, out2, zero_off, n);
    k_conv2<<<cg, 256, 0, stream>>>(h2s, ell, cnt, b2,
                                    out1, zero_off, n);
}